// Round 11
// baseline (277.318 us; speedup 1.0000x reference)
//
#include <hip/hip_runtime.h>
#include <math.h>

#define D_DIM 16
#define N_PTS 100
#define VMIN_F (-5.0f)
#define INT_LEN_F (10.0f / 99.0f)
#define INV_INT_LEN_F (99.0f / 10.0f)

// clang ext-vector type (round-2 lesson: HIP float4 is a struct, rejected by
// register-tuple asm/builtin paths; ext-vector maps to 4 consecutive VGPRs).
typedef float f32x4_t __attribute__((ext_vector_type(4)));

// Nontemporal output store via INLINE ASM `nt` flag (cdna4_isa §7: global_*
// takes nt; sc0/sc1/nt are the gfx950 spellings — glc/slc do not assemble).
// Rationale: output is write-once-never-read; LLC allocation is pure
// pollution. Harness calibration: non-allocating write stream (fill) drains
// 6.7 TB/s; our allocating write stream has never exceeded ~1.65 TB/s.
// Why asm, not __builtin_nontemporal_store: 4 of 5 submissions containing
// the builtin hit container-level failures (R1/R7/R8/R9; R3 ran). Whether
// that is causal or a bad-node streak, this is a different compiler path,
// and a malformed-asm outcome is a clean compile error (R2 precedent).
__device__ __forceinline__ void nt_store4(float4* p, float o0, float o1,
                                          float o2, float o3) {
    f32x4_t v = {o0, o1, o2, o3};
    asm volatile("global_store_dwordx4 %0, %1, off nt"
                 :: "v"(p), "v"(v) : "memory");
}

// ---------------------------------------------------------------------------
// Setup kernel (1 block, 256 threads) — unchanged (verified):
//  - Gauss-Jordan inverse of (I - A) in fp64 (partial pivoting) -> Minv [16x16]
//  - Combined PWL table Ctab[d][idx] = { w(idx), delta_bias(max(idx-1,0)) }
// ---------------------------------------------------------------------------
__global__ void scm_setup(const float* __restrict__ A,
                          const float* __restrict__ p,
                          const float* __restrict__ b,
                          float* __restrict__ Minv,
                          float2* __restrict__ Ctab) {
    __shared__ double aug[16][33];   // [I-A | I], padded
    __shared__ float db_s[16][N_PTS];
    __shared__ int piv;
    const int t = threadIdx.x;

    if (t < 16) {
        #pragma unroll
        for (int j = 0; j < 16; j++) {
            aug[t][j]      = (t == j ? 1.0 : 0.0) - (double)A[t * 16 + j];
            aug[t][16 + j] = (t == j ? 1.0 : 0.0);
        }
    }
    __syncthreads();

    for (int k = 0; k < 16; k++) {
        if (t == 0) {
            int pr = k; double best = fabs(aug[k][k]);
            for (int i = k + 1; i < 16; i++) {
                double v = fabs(aug[i][k]);
                if (v > best) { best = v; pr = i; }
            }
            piv = pr;
        }
        __syncthreads();
        const int pr = piv;
        if (pr != k && t < 32) {
            double tmp = aug[k][t]; aug[k][t] = aug[pr][t]; aug[pr][t] = tmp;
        }
        __syncthreads();
        const double pivval = aug[k][k];
        __syncthreads();
        if (t < 32) aug[k][t] = aug[k][t] / pivval;
        __syncthreads();
        if (t < 16 && t != k) {
            const double f = aug[t][k];
            #pragma unroll
            for (int j = 0; j < 32; j++) aug[t][j] -= f * aug[k][j];
        }
        __syncthreads();
    }

    if (t < 16) {
        #pragma unroll
        for (int j = 0; j < 16; j++) Minv[t * 16 + j] = (float)aug[t][16 + j];
    }

    // serial per-dim fp32 cumsum (matches reference jnp.cumsum ordering)
    if (t < 16) {
        float acc = b[t];
        db_s[t][0] = acc;
        for (int i = 1; i < N_PTS; i++) {
            acc += INT_LEN_F * (expf(p[t * (N_PTS + 1) + i]) + 0.001f);
            db_s[t][i] = acc;
        }
    }
    __syncthreads();

    // combined table: one float2 per (d, idx)
    for (int i = t; i < 16 * (N_PTS + 1); i += blockDim.x) {
        const int d   = i / (N_PTS + 1);
        const int idx = i - d * (N_PTS + 1);
        const int spi = idx > 0 ? idx - 1 : 0;
        float2 c;
        c.x = expf(p[i]) + 0.001f;   // w at idx
        c.y = db_s[d][spi];          // delta_bias at sp_idx
        Ctab[i] = c;
    }
}

// DPP quad_perm broadcast: every lane in an aligned quad receives lane J's x.
// Pure VALU (no LDS pipe). Quads are always fully active together.
template <int J>
__device__ __forceinline__ float dpp_bcast(float x) {
    constexpr int ctrl = J | (J << 2) | (J << 4) | (J << 6);  // quad_perm
    int xi = __builtin_bit_cast(int, x);
    int r  = __builtin_amdgcn_mov_dpp(xi, ctrl, 0xf, 0xf, true);
    return __builtin_bit_cast(float, r);
}

// ---------------------------------------------------------------------------
// Main kernel, v9 (= verified v5 structure + PLAIN loads + ASM-nt stores):
//  R10 post-mortem: grid 4096 null; scm_main <75.6 µs at ~3.3 TB/s mixed.
//  Theory: write stream allocating in LLC caps write drain (~1.65 TB/s ever
//  observed) vs 6.7 TB/s for the non-allocating fill. With nt WRITES the
//  input can stay L3-resident across bench iterations under PLAIN loads
//  (R5: FETCH 66.7 MB < 128 MB input), so reads come from L3 and writes
//  stream at fill-rate: predicted scm_main 35-55 µs.
//  Structure FROZEN: UF=2 named scalars (spill-proof, VGPR=60), Minv in
//  LDS k-outer, sC LDS table, grid 4096.
// ---------------------------------------------------------------------------
__global__ __launch_bounds__(256, 4) void scm_main(
        const float* __restrict__ eps,
        const float* __restrict__ Minv,
        const float2* __restrict__ Ctab,
        float* __restrict__ out, int B) {
    __shared__ float2 sC[16 * (N_PTS + 1)];   // 12928 B
    __shared__ float4 sM[64];                 // 1024 B; sM[k*4+q] = Minv[k][4q..4q+3]

    const int t = threadIdx.x;
    const int q = t & 3;                      // quarter within row

    for (int i = t; i < 16 * (N_PTS + 1); i += 256) sC[i] = Ctab[i];
    ((float*)sM)[t] = Minv[t];                // flat copy == desired layout
    __syncthreads();

    const float4* sMq = sM + q;               // sMq[4*k] = Minv[k][4q..4q+3]

    const int total  = B * 4;                 // float4 count (8M, fits int)
    const int stride = (int)gridDim.x * 256;
    const int sstep  = stride * 2;            // two rows per iteration
    int base = (int)blockIdx.x * 256 + t;

    const float4* in4  = (const float4*)eps;
    float4*       out4 = (float4*)out;

    const float4 zero4 = make_float4(0.f, 0.f, 0.f, 0.f);

    float4 curA = (base < total)          ? in4[base]          : zero4;
    float4 curB = (base + stride < total) ? in4[base + stride] : zero4;

    for (; base < total; base += sstep) {
        // prefetch next pair (2 loads in flight across this iteration's compute)
        const int nb = base + sstep;
        float4 nxtA = (nb < total)          ? in4[nb]          : zero4;
        float4 nxtB = (nb + stride < total) ? in4[nb + stride] : zero4;

        float4 zA = zero4;
        float4 zB = zero4;

        // k-outer: one ds_read_b128 of the Minv row-quarter per k, reused by
        // both rows; 8 independent FMA chains. e[k=4G+C] = dpp_bcast<G>(comp C).
#define SCM_STEP(G, C, COMP)                                                   \
        {                                                                      \
            const float4 mk = sMq[4 * (4 * (G) + (C))];                        \
            const float eA = dpp_bcast<(G)>(curA.COMP);                        \
            const float eB = dpp_bcast<(G)>(curB.COMP);                        \
            zA.x = fmaf(eA, mk.x, zA.x); zA.y = fmaf(eA, mk.y, zA.y);          \
            zA.z = fmaf(eA, mk.z, zA.z); zA.w = fmaf(eA, mk.w, zA.w);          \
            zB.x = fmaf(eB, mk.x, zB.x); zB.y = fmaf(eB, mk.y, zB.y);          \
            zB.z = fmaf(eB, mk.z, zB.z); zB.w = fmaf(eB, mk.w, zB.w);          \
        }
        SCM_STEP(0, 0, x) SCM_STEP(0, 1, y) SCM_STEP(0, 2, z) SCM_STEP(0, 3, w)
        SCM_STEP(1, 0, x) SCM_STEP(1, 1, y) SCM_STEP(1, 2, z) SCM_STEP(1, 3, w)
        SCM_STEP(2, 0, x) SCM_STEP(2, 1, y) SCM_STEP(2, 2, z) SCM_STEP(2, 3, w)
        SCM_STEP(3, 0, x) SCM_STEP(3, 1, y) SCM_STEP(3, 2, z) SCM_STEP(3, 3, w)
#undef SCM_STEP

        // PWL + store, row A then row B (all scalars, no arrays)
#define SCM_PWL_STORE(ZV, IDX)                                                 \
        if ((IDX) < total) {                                                   \
            float o0, o1, o2, o3;                                              \
            {                                                                  \
                const float zd = (ZV).x;                                       \
                int id = (int)floorf((zd - VMIN_F) * INV_INT_LEN_F) + 1;       \
                id = min(max(id, 0), N_PTS);                                   \
                const int spi = max(id - 1, 0);                                \
                const float sp = VMIN_F + (float)spi * INT_LEN_F;              \
                const float2 c = sC[(4 * q + 0) * (N_PTS + 1) + id];           \
                o0 = fmaf(zd - sp, c.x, c.y);                                  \
            }                                                                  \
            {                                                                  \
                const float zd = (ZV).y;                                       \
                int id = (int)floorf((zd - VMIN_F) * INV_INT_LEN_F) + 1;       \
                id = min(max(id, 0), N_PTS);                                   \
                const int spi = max(id - 1, 0);                                \
                const float sp = VMIN_F + (float)spi * INT_LEN_F;              \
                const float2 c = sC[(4 * q + 1) * (N_PTS + 1) + id];           \
                o1 = fmaf(zd - sp, c.x, c.y);                                  \
            }                                                                  \
            {                                                                  \
                const float zd = (ZV).z;                                       \
                int id = (int)floorf((zd - VMIN_F) * INV_INT_LEN_F) + 1;       \
                id = min(max(id, 0), N_PTS);                                   \
                const int spi = max(id - 1, 0);                                \
                const float sp = VMIN_F + (float)spi * INT_LEN_F;              \
                const float2 c = sC[(4 * q + 2) * (N_PTS + 1) + id];           \
                o2 = fmaf(zd - sp, c.x, c.y);                                  \
            }                                                                  \
            {                                                                  \
                const float zd = (ZV).w;                                       \
                int id = (int)floorf((zd - VMIN_F) * INV_INT_LEN_F) + 1;       \
                id = min(max(id, 0), N_PTS);                                   \
                const int spi = max(id - 1, 0);                                \
                const float sp = VMIN_F + (float)spi * INT_LEN_F;              \
                const float2 c = sC[(4 * q + 3) * (N_PTS + 1) + id];           \
                o3 = fmaf(zd - sp, c.x, c.y);                                  \
            }                                                                  \
            nt_store4(out4 + (IDX), o0, o1, o2, o3);                           \
        }

        SCM_PWL_STORE(zA, base)
        SCM_PWL_STORE(zB, base + stride)
#undef SCM_PWL_STORE

        curA = nxtA;
        curB = nxtB;
    }
}

extern "C" void kernel_launch(void* const* d_in, const int* in_sizes, int n_in,
                              void* d_out, int out_size, void* d_ws, size_t ws_size,
                              hipStream_t stream) {
    const float* eps = (const float*)d_in[0];
    const float* A   = (const float*)d_in[1];
    const float* p   = (const float*)d_in[2];
    const float* b   = (const float*)d_in[3];
    float* out = (float*)d_out;

    const int B = in_sizes[0] / D_DIM;

    // workspace layout: Minv[256 floats] | Ctab[16*101 float2] (8B-aligned)
    float*  ws   = (float*)d_ws;
    float*  Minv = ws;
    float2* Ctab = (float2*)(ws + 256);

    scm_setup<<<1, 256, 0, stream>>>(A, p, b, Minv, Ctab);

    long total_f4 = (long)B * 4;
    int blocks = (int)((total_f4 + 255) / 256);
    if (blocks > 4096) blocks = 4096;
    if (blocks < 1) blocks = 1;
    scm_main<<<blocks, 256, 0, stream>>>(eps, Minv, Ctab, out, B);
}

// Round 12
// 270.749 us; speedup vs baseline: 1.0243x; 1.0243x over previous
//
#include <hip/hip_runtime.h>
#include <math.h>

#define D_DIM 16
#define N_PTS 100
#define VMIN_F (-5.0f)
#define INT_LEN_F (10.0f / 99.0f)
#define INV_INT_LEN_F (99.0f / 10.0f)

// clang ext-vector type: REQUIRED for __builtin_nontemporal_* — HIP's float4
// (HIP_vector_type struct) is rejected by the builtins (round-2 lesson).
typedef float f32x4_t __attribute__((ext_vector_type(4)));

// Nontemporal input load: no L2/L3 allocate. Input is streamed once; keeping
// it out of the LLC frees capacity for the write stream. R6 evidence:
// scm_main dropped 82 -> <76 µs with these (best known).
//
// nt-STORE: permanently EXCLUDED. R11 falsified the write-LLC theory: asm-nt
// stores left the write drain at ~1.6 TB/s (identical to plain stores and to
// rocclr copyBuffer's write rate) and cost ~5 µs in scheduling freedom.
// The ~1.6 TB/s write component under a concurrent read stream is a
// platform-level mixed-stream property (AMD's own copy kernel reproduces it).
__device__ __forceinline__ float4 nt_load4(const float4* p) {
    f32x4_t v = __builtin_nontemporal_load((const f32x4_t*)p);
    return make_float4(v.x, v.y, v.z, v.w);
}

// ---------------------------------------------------------------------------
// Setup kernel (1 block, 256 threads) — unchanged (verified):
//  - Gauss-Jordan inverse of (I - A) in fp64 (partial pivoting) -> Minv [16x16]
//  - Combined PWL table Ctab[d][idx] = { w(idx), delta_bias(max(idx-1,0)) }
// ---------------------------------------------------------------------------
__global__ void scm_setup(const float* __restrict__ A,
                          const float* __restrict__ p,
                          const float* __restrict__ b,
                          float* __restrict__ Minv,
                          float2* __restrict__ Ctab) {
    __shared__ double aug[16][33];   // [I-A | I], padded
    __shared__ float db_s[16][N_PTS];
    __shared__ int piv;
    const int t = threadIdx.x;

    if (t < 16) {
        #pragma unroll
        for (int j = 0; j < 16; j++) {
            aug[t][j]      = (t == j ? 1.0 : 0.0) - (double)A[t * 16 + j];
            aug[t][16 + j] = (t == j ? 1.0 : 0.0);
        }
    }
    __syncthreads();

    for (int k = 0; k < 16; k++) {
        if (t == 0) {
            int pr = k; double best = fabs(aug[k][k]);
            for (int i = k + 1; i < 16; i++) {
                double v = fabs(aug[i][k]);
                if (v > best) { best = v; pr = i; }
            }
            piv = pr;
        }
        __syncthreads();
        const int pr = piv;
        if (pr != k && t < 32) {
            double tmp = aug[k][t]; aug[k][t] = aug[pr][t]; aug[pr][t] = tmp;
        }
        __syncthreads();
        const double pivval = aug[k][k];
        __syncthreads();
        if (t < 32) aug[k][t] = aug[k][t] / pivval;
        __syncthreads();
        if (t < 16 && t != k) {
            const double f = aug[t][k];
            #pragma unroll
            for (int j = 0; j < 32; j++) aug[t][j] -= f * aug[k][j];
        }
        __syncthreads();
    }

    if (t < 16) {
        #pragma unroll
        for (int j = 0; j < 16; j++) Minv[t * 16 + j] = (float)aug[t][16 + j];
    }

    // serial per-dim fp32 cumsum (matches reference jnp.cumsum ordering)
    if (t < 16) {
        float acc = b[t];
        db_s[t][0] = acc;
        for (int i = 1; i < N_PTS; i++) {
            acc += INT_LEN_F * (expf(p[t * (N_PTS + 1) + i]) + 0.001f);
            db_s[t][i] = acc;
        }
    }
    __syncthreads();

    // combined table: one float2 per (d, idx)
    for (int i = t; i < 16 * (N_PTS + 1); i += blockDim.x) {
        const int d   = i / (N_PTS + 1);
        const int idx = i - d * (N_PTS + 1);
        const int spi = idx > 0 ? idx - 1 : 0;
        float2 c;
        c.x = expf(p[i]) + 0.001f;   // w at idx
        c.y = db_s[d][spi];          // delta_bias at sp_idx
        Ctab[i] = c;
    }
}

// DPP quad_perm broadcast: every lane in an aligned quad receives lane J's x.
// Pure VALU (no LDS pipe). Quads are always fully active together.
template <int J>
__device__ __forceinline__ float dpp_bcast(float x) {
    constexpr int ctrl = J | (J << 2) | (J << 4) | (J << 6);  // quad_perm
    int xi = __builtin_bit_cast(int, x);
    int r  = __builtin_amdgcn_mov_dpp(xi, ctrl, 0xf, 0xf, true);
    return __builtin_bit_cast(float, r);
}

// ---------------------------------------------------------------------------
// Main kernel, v10 = REVERT to R10's v8 (best verified: bench 270-272,
// scm_main <75.6 µs, beats rocclr copyBuffer ~30%/byte on the same streams).
//  Session ledger of levers (all within-harness measured):
//   - prefetch depth 1/2/4: null (R0=R5); arrays->scratch catastrophic (R3/4)
//   - Minv in LDS vs VGPR: fixed the VGPR=56 demotion, null on time
//   - nt-load: -6 µs (kept)   - nt-store (asm): +5 µs, drain unchanged (out)
//   - grid 2048->4096: null (kept, harmless)
//  Ceiling: 250 MB min traffic / 3.7 TB/s empirical mixed-stream ceiling
//  (ours R3/R4/R6 + rocclr copy all agree) = 68 µs floor; we're at ~90%.
// ---------------------------------------------------------------------------
__global__ __launch_bounds__(256, 4) void scm_main(
        const float* __restrict__ eps,
        const float* __restrict__ Minv,
        const float2* __restrict__ Ctab,
        float* __restrict__ out, int B) {
    __shared__ float2 sC[16 * (N_PTS + 1)];   // 12928 B
    __shared__ float4 sM[64];                 // 1024 B; sM[k*4+q] = Minv[k][4q..4q+3]

    const int t = threadIdx.x;
    const int q = t & 3;                      // quarter within row

    for (int i = t; i < 16 * (N_PTS + 1); i += 256) sC[i] = Ctab[i];
    ((float*)sM)[t] = Minv[t];                // flat copy == desired layout
    __syncthreads();

    const float4* sMq = sM + q;               // sMq[4*k] = Minv[k][4q..4q+3]

    const int total  = B * 4;                 // float4 count (8M, fits int)
    const int stride = (int)gridDim.x * 256;
    const int sstep  = stride * 2;            // two rows per iteration
    int base = (int)blockIdx.x * 256 + t;

    const float4* in4  = (const float4*)eps;
    float4*       out4 = (float4*)out;

    const float4 zero4 = make_float4(0.f, 0.f, 0.f, 0.f);

    float4 curA = (base < total)          ? nt_load4(in4 + base)          : zero4;
    float4 curB = (base + stride < total) ? nt_load4(in4 + base + stride) : zero4;

    for (; base < total; base += sstep) {
        // prefetch next pair (2 loads in flight across this iteration's compute)
        const int nb = base + sstep;
        float4 nxtA = (nb < total)          ? nt_load4(in4 + nb)          : zero4;
        float4 nxtB = (nb + stride < total) ? nt_load4(in4 + nb + stride) : zero4;

        float4 zA = zero4;
        float4 zB = zero4;

        // k-outer: one ds_read_b128 of the Minv row-quarter per k, reused by
        // both rows; 8 independent FMA chains. e[k=4G+C] = dpp_bcast<G>(comp C).
#define SCM_STEP(G, C, COMP)                                                   \
        {                                                                      \
            const float4 mk = sMq[4 * (4 * (G) + (C))];                        \
            const float eA = dpp_bcast<(G)>(curA.COMP);                        \
            const float eB = dpp_bcast<(G)>(curB.COMP);                        \
            zA.x = fmaf(eA, mk.x, zA.x); zA.y = fmaf(eA, mk.y, zA.y);          \
            zA.z = fmaf(eA, mk.z, zA.z); zA.w = fmaf(eA, mk.w, zA.w);          \
            zB.x = fmaf(eB, mk.x, zB.x); zB.y = fmaf(eB, mk.y, zB.y);          \
            zB.z = fmaf(eB, mk.z, zB.z); zB.w = fmaf(eB, mk.w, zB.w);          \
        }
        SCM_STEP(0, 0, x) SCM_STEP(0, 1, y) SCM_STEP(0, 2, z) SCM_STEP(0, 3, w)
        SCM_STEP(1, 0, x) SCM_STEP(1, 1, y) SCM_STEP(1, 2, z) SCM_STEP(1, 3, w)
        SCM_STEP(2, 0, x) SCM_STEP(2, 1, y) SCM_STEP(2, 2, z) SCM_STEP(2, 3, w)
        SCM_STEP(3, 0, x) SCM_STEP(3, 1, y) SCM_STEP(3, 2, z) SCM_STEP(3, 3, w)
#undef SCM_STEP

        // PWL + store, row A then row B (all scalars, no arrays)
#define SCM_PWL_STORE(ZV, IDX)                                                 \
        if ((IDX) < total) {                                                   \
            float o0, o1, o2, o3;                                              \
            {                                                                  \
                const float zd = (ZV).x;                                       \
                int id = (int)floorf((zd - VMIN_F) * INV_INT_LEN_F) + 1;       \
                id = min(max(id, 0), N_PTS);                                   \
                const int spi = max(id - 1, 0);                                \
                const float sp = VMIN_F + (float)spi * INT_LEN_F;              \
                const float2 c = sC[(4 * q + 0) * (N_PTS + 1) + id];           \
                o0 = fmaf(zd - sp, c.x, c.y);                                  \
            }                                                                  \
            {                                                                  \
                const float zd = (ZV).y;                                       \
                int id = (int)floorf((zd - VMIN_F) * INV_INT_LEN_F) + 1;       \
                id = min(max(id, 0), N_PTS);                                   \
                const int spi = max(id - 1, 0);                                \
                const float sp = VMIN_F + (float)spi * INT_LEN_F;              \
                const float2 c = sC[(4 * q + 1) * (N_PTS + 1) + id];           \
                o1 = fmaf(zd - sp, c.x, c.y);                                  \
            }                                                                  \
            {                                                                  \
                const float zd = (ZV).z;                                       \
                int id = (int)floorf((zd - VMIN_F) * INV_INT_LEN_F) + 1;       \
                id = min(max(id, 0), N_PTS);                                   \
                const int spi = max(id - 1, 0);                                \
                const float sp = VMIN_F + (float)spi * INT_LEN_F;              \
                const float2 c = sC[(4 * q + 2) * (N_PTS + 1) + id];           \
                o2 = fmaf(zd - sp, c.x, c.y);                                  \
            }                                                                  \
            {                                                                  \
                const float zd = (ZV).w;                                       \
                int id = (int)floorf((zd - VMIN_F) * INV_INT_LEN_F) + 1;       \
                id = min(max(id, 0), N_PTS);                                   \
                const int spi = max(id - 1, 0);                                \
                const float sp = VMIN_F + (float)spi * INT_LEN_F;              \
                const float2 c = sC[(4 * q + 3) * (N_PTS + 1) + id];           \
                o3 = fmaf(zd - sp, c.x, c.y);                                  \
            }                                                                  \
            out4[(IDX)] = make_float4(o0, o1, o2, o3);                         \
        }

        SCM_PWL_STORE(zA, base)
        SCM_PWL_STORE(zB, base + stride)
#undef SCM_PWL_STORE

        curA = nxtA;
        curB = nxtB;
    }
}

extern "C" void kernel_launch(void* const* d_in, const int* in_sizes, int n_in,
                              void* d_out, int out_size, void* d_ws, size_t ws_size,
                              hipStream_t stream) {
    const float* eps = (const float*)d_in[0];
    const float* A   = (const float*)d_in[1];
    const float* p   = (const float*)d_in[2];
    const float* b   = (const float*)d_in[3];
    float* out = (float*)d_out;

    const int B = in_sizes[0] / D_DIM;

    // workspace layout: Minv[256 floats] | Ctab[16*101 float2] (8B-aligned)
    float*  ws   = (float*)d_ws;
    float*  Minv = ws;
    float2* Ctab = (float2*)(ws + 256);

    scm_setup<<<1, 256, 0, stream>>>(A, p, b, Minv, Ctab);

    long total_f4 = (long)B * 4;
    int blocks = (int)((total_f4 + 255) / 256);
    if (blocks > 4096) blocks = 4096;
    if (blocks < 1) blocks = 1;
    scm_main<<<blocks, 256, 0, stream>>>(eps, Minv, Ctab, out, B);
}